// Round 6
// baseline (250.719 us; speedup 1.0000x reference)
//
#include <hip/hip_runtime.h>
#include <math.h>

#define KK 9
#define BB 8
#define CC 64
#define OO 64
#define HH 128
#define WW 128
#define HWSZ (HH*WW)

typedef _Float16 half8 __attribute__((ext_vector_type(8)));
typedef float    floatx4 __attribute__((ext_vector_type(4)));

// ws layout (f16): Wp[32][576] | Wd[9][64][64] | x_h[B][HW][64]
#define WP_ELEMS (32*576)
#define WD_ELEMS (9*64*64)
#define XH_ELEMS ((size_t)BB*HWSZ*64)

// ---------------- prep: weight repack (f16) + x -> channel-last f16 ----------------
// blocks [0,2048): convert 64px x 64ch tile via LDS transpose; [2048, 2048+216): repack
#define NCONV 2048
__global__ __launch_bounds__(256) void prep(
    const float* __restrict__ x,
    const float* __restrict__ p_w, const float* __restrict__ m_w,
    const float* __restrict__ d_w,
    _Float16* __restrict__ Wp, _Float16* __restrict__ Wd, _Float16* __restrict__ x_h)
{
    const int blk = blockIdx.x;
    const int tid = threadIdx.x;
    if (blk < NCONV) {
        __shared__ _Float16 sh[64][72];
        const int b    = blk >> 8;
        const int pix0 = (blk & 255) * 64;
        const float* xb = x + (size_t)b*CC*HWSZ + pix0;
        {
            const int p     = tid & 63;
            const int cbase = tid >> 6;
            #pragma unroll
            for (int j = 0; j < 16; ++j) {
                const int c = j*4 + cbase;
                sh[p][c] = (_Float16)xb[(size_t)c*HWSZ + p];
            }
        }
        __syncthreads();
        {
            const int p  = tid >> 2;
            const int c0 = (tid & 3) * 16;
            _Float16* dst = x_h + ((size_t)b*HWSZ + pix0 + p)*64 + c0;
            *(half8*)dst       = *(const half8*)&sh[p][c0];
            *(half8*)(dst + 8) = *(const half8*)&sh[p][c0 + 8];
        }
    } else {
        const int i = (blk - NCONV)*256 + tid;
        if (i < WP_ELEMS) {
            int n = i / 576, r = i % 576;
            int k = r >> 6, c = r & 63;
            float v = 0.f;
            if (n < 18)      v = p_w[(n*CC + c)*KK + k];
            else if (n < 27) v = m_w[((n-18)*CC + c)*KK + k];
            Wp[i] = (_Float16)v;
        } else if (i < WP_ELEMS + WD_ELEMS) {
            int j = i - WP_ELEMS;
            int k = j / 4096, r = j % 4096, o = r >> 6, c = r & 63;  // Wd[k][o][c]
            Wd[j] = (_Float16)d_w[(o*CC + c)*KK + k];
        }
    }
}

// ---------------- fused DCNv2, register-direct MFMA fragments, barrier-free loops ----------------
// flat grid 1024; b = blk & 7 (XCD swizzle); block = one image row (128 px),
// 4 waves x 32 px (mt=2). A/B fragments loaded straight from global; LDS only for
// the 27-channel offset/mask table and the output transpose.
__global__ __launch_bounds__(256, 3) void dcn_fused(
    const _Float16* __restrict__ x_h,
    const _Float16* __restrict__ Wp, const _Float16* __restrict__ Wd,
    const float* __restrict__ p_b, const float* __restrict__ m_b,
    const float* __restrict__ db,
    float* __restrict__ out, float* __restrict__ offset_out)
{
    __shared__ float Off[27][132];   // offset/mask table; epilogue-2 aliases rows [0,16)

    const int tid  = threadIdx.x;
    const int wv   = tid >> 6;
    const int lane = tid & 63;
    const int quad = lane >> 4;
    const int l15  = lane & 15;
    const int b    = blockIdx.x & 7;
    const int row  = blockIdx.x >> 3;
    const int pix0 = row * WW;
    const _Float16* xbh = x_h + (size_t)b*HWSZ*64;

    // =============== phase 1: offset(18)+mask(9) conv, no LDS, no barriers ===============
    floatx4 accp[2][2];
    #pragma unroll
    for (int mt = 0; mt < 2; ++mt)
        #pragma unroll
        for (int nt = 0; nt < 2; ++nt) accp[mt][nt] = (floatx4)0.f;

    #pragma unroll 3
    for (int k = 0; k < 9; ++k) {
        const int hy = row + k/3 - 1;
        const int dw = k%3 - 1;
        const bool vy = (hy >= 0) & (hy < HH);
        // B fragments straight from Wp (L2-broadcast)
        half8 bp[2][2];
        #pragma unroll
        for (int nt = 0; nt < 2; ++nt)
            #pragma unroll
            for (int ks = 0; ks < 2; ++ks)
                bp[nt][ks] = *(const half8*)(Wp + (nt*16 + l15)*576 + k*64 + ks*32 + quad*8);
        #pragma unroll
        for (int mt = 0; mt < 2; ++mt) {
            const int P  = wv*32 + mt*16 + l15;       // pixel in row == w coord
            const int wx = P + dw;
            const bool v = vy & (wx >= 0) & (wx < WW);
            const _Float16* ap = xbh + ((size_t)(hy*WW + wx))*64;
            #pragma unroll
            for (int ks = 0; ks < 2; ++ks) {
                half8 av = v ? *(const half8*)(ap + ks*32 + quad*8) : (half8)(_Float16)0.f;
                accp[mt][0] = __builtin_amdgcn_mfma_f32_16x16x32_f16(av, bp[0][ks], accp[mt][0], 0, 0, 0);
                accp[mt][1] = __builtin_amdgcn_mfma_f32_16x16x32_f16(av, bp[1][ks], accp[mt][1], 0, 0, 0);
            }
        }
    }

    // epilogue 1: D-frags -> Off table with bias (+sigmoid for mask rows)
    #pragma unroll
    for (int nt = 0; nt < 2; ++nt) {
        const int ch = nt*16 + l15;
        if (ch < 27) {
            const float bias = (ch < 18) ? p_b[ch] : m_b[ch-18];
            #pragma unroll
            for (int mt = 0; mt < 2; ++mt)
                #pragma unroll
                for (int r = 0; r < 4; ++r) {
                    float v = accp[mt][nt][r] + bias;
                    if (ch >= 18) v = 1.f / (1.f + expf(-v));
                    Off[ch][wv*32 + mt*16 + quad*4 + r] = v;
                }
        }
    }
    __syncthreads();

    // write offsets to global (18*128 = 2304 floats, coalesced per row)
    {
        float* offp = offset_out + (size_t)b*18*HWSZ + pix0;
        #pragma unroll
        for (int j = 0; j < 9; ++j) {
            const int idx = j*256 + tid;
            const int ch = idx >> 7, p = idx & 127;
            offp[ch*HWSZ + p] = Off[ch][p];
        }
    }

    // =============== phase 2: deformable conv, register-direct, no barriers ===============
    floatx4 acc[2][4];
    #pragma unroll
    for (int mt = 0; mt < 2; ++mt)
        #pragma unroll
        for (int nt = 0; nt < 4; ++nt) acc[mt][nt] = (floatx4)0.f;

    #pragma unroll 3
    for (int k = 0; k < 9; ++k) {
        half8 bd[4][2];
        #pragma unroll
        for (int nt = 0; nt < 4; ++nt)
            #pragma unroll
            for (int ks = 0; ks < 2; ++ks)
                bd[nt][ks] = *(const half8*)(Wd + k*4096 + (nt*16 + l15)*64 + ks*32 + quad*8);

        #pragma unroll
        for (int mt = 0; mt < 2; ++mt) {
            const int P = wv*32 + mt*16 + l15;
            const float dyk = Off[2*k][P];
            const float dxk = Off[2*k+1][P];
            const float mk  = Off[18+k][P];
            const float py = (float)(row - 1 + k/3) + dyk;
            const float px = (float)(P   - 1 + k%3) + dxk;
            const float y0f = floorf(py), x0f = floorf(px);
            const int   iy0 = (int)y0f,   ix0 = (int)x0f;
            const float wy1 = py - y0f,   wx1 = px - x0f;
            const float wy0 = 1.f - wy1,  wx0 = 1.f - wx1;
            const bool vy0 = (iy0   >= 0) & (iy0   < HH);
            const bool vy1 = (iy0+1 >= 0) & (iy0+1 < HH);
            const bool vx0 = (ix0   >= 0) & (ix0   < WW);
            const bool vx1 = (ix0+1 >= 0) & (ix0+1 < WW);
            const int cy0 = min(max(iy0,   0), HH-1), cy1 = min(max(iy0+1, 0), HH-1);
            const int cx0 = min(max(ix0,   0), WW-1), cx1 = min(max(ix0+1, 0), WW-1);
            const int i0 = cy0*WW+cx0; const float w0 = wy0*wx0*((vy0&vx0) ? mk : 0.f);
            const int i1 = cy0*WW+cx1; const float w1 = wy0*wx1*((vy0&vx1) ? mk : 0.f);
            const int i2 = cy1*WW+cx0; const float w2 = wy1*wx0*((vy1&vx0) ? mk : 0.f);
            const int i3 = cy1*WW+cx1; const float w3 = wy1*wx1*((vy1&vx1) ? mk : 0.f);
            const _Float16 h0 = (_Float16)w0, h1 = (_Float16)w1,
                           h2 = (_Float16)w2, h3 = (_Float16)w3;
            const _Float16* c0 = xbh + (size_t)i0*64;
            const _Float16* c1 = xbh + (size_t)i1*64;
            const _Float16* c2 = xbh + (size_t)i2*64;
            const _Float16* c3 = xbh + (size_t)i3*64;
            #pragma unroll
            for (int ks = 0; ks < 2; ++ks) {
                const int co = ks*32 + quad*8;
                half8 av = *(const half8*)(c0 + co) * h0
                         + *(const half8*)(c1 + co) * h1
                         + *(const half8*)(c2 + co) * h2
                         + *(const half8*)(c3 + co) * h3;
                #pragma unroll
                for (int nt = 0; nt < 4; ++nt)
                    acc[mt][nt] = __builtin_amdgcn_mfma_f32_16x16x32_f16(av, bd[nt][ks], acc[mt][nt], 0, 0, 0);
            }
        }
    }
    __syncthreads();   // Off reads done block-wide before aliasing as T2

    // epilogue 2: 4 chunks of 16 output channels via LDS transpose
    float (*T2)[132] = (float (*)[132])&Off[0][0];
    #pragma unroll
    for (int oc = 0; oc < 4; ++oc) {
        #pragma unroll
        for (int mt = 0; mt < 2; ++mt)
            #pragma unroll
            for (int r = 0; r < 4; ++r)
                T2[l15][wv*32 + mt*16 + quad*4 + r] = acc[mt][oc][r];
        __syncthreads();
        #pragma unroll
        for (int j = 0; j < 8; ++j) {
            const int idx = tid + j*256;
            const int o16 = idx >> 7, p2 = idx & 127;
            out[((size_t)b*OO + oc*16 + o16)*HWSZ + pix0 + p2] = T2[o16][p2] + db[oc*16 + o16];
        }
        __syncthreads();
    }
}

// ---------------- fallback (ws too small): R5-style LDS kernel, fp32 gather ----------------
__global__ __launch_bounds__(256, 4) void dcn_fused_lds(
    const float* __restrict__ x,
    const _Float16* __restrict__ Wp, const _Float16* __restrict__ Wd,
    const float* __restrict__ p_b, const float* __restrict__ m_b,
    const float* __restrict__ db,
    float* __restrict__ out, float* __restrict__ offset_out)
{
    __shared__ alignas(16) _Float16 A_sh[128][72];
    __shared__ alignas(16) _Float16 WM_sh[32*72];
    __shared__ alignas(16) _Float16 Wd_sh[64][72];

    const int tid   = threadIdx.x;
    const int wv    = tid >> 6;
    const int lane  = tid & 63;
    const int quad  = lane >> 4;
    const int l15   = lane & 15;
    const int b     = blockIdx.x & 7;
    const int row   = blockIdx.x >> 3;
    const int pix0  = row * WW;
    const int p     = tid & 127;
    const int chalf = (tid >> 7) * 32;
    const int h = row, w = p;
    const float* xb = x + (size_t)b*CC*HWSZ;
    _Float16 (*W_sh)[72] = (_Float16 (*)[72])WM_sh;

    floatx4 accp[2][2];
    #pragma unroll
    for (int mt = 0; mt < 2; ++mt)
        #pragma unroll
        for (int nt = 0; nt < 2; ++nt) accp[mt][nt] = (floatx4)0.f;

    for (int k = 0; k < 9; ++k) {
        {
            const int n  = tid >> 3;
            const int c0 = (tid & 7) * 8;
            *(half8*)&W_sh[n][c0] = *(const half8*)(Wp + n*576 + k*64 + c0);
        }
        const int hy = h + (k/3) - 1;
        const int wx = w + (k%3) - 1;
        const bool vld = (hy >= 0) & (hy < HH) & (wx >= 0) & (wx < WW);
        const float* xs = xb + hy*WW + wx;
        #pragma unroll
        for (int cb = 0; cb < 4; ++cb) {
            union { half8 v; _Float16 e[8]; } u;
            #pragma unroll
            for (int j = 0; j < 8; ++j)
                u.e[j] = (_Float16)(vld ? xs[(size_t)(chalf + cb*8 + j)*HWSZ] : 0.f);
            *(half8*)&A_sh[p][chalf + cb*8] = u.v;
        }
        __syncthreads();
        #pragma unroll
        for (int ks = 0; ks < 2; ++ks) {
            half8 bf[2];
            #pragma unroll
            for (int nt = 0; nt < 2; ++nt)
                bf[nt] = *(const half8*)&W_sh[nt*16 + l15][ks*32 + quad*8];
            #pragma unroll
            for (int mt = 0; mt < 2; ++mt) {
                half8 af = *(const half8*)&A_sh[wv*32 + mt*16 + l15][ks*32 + quad*8];
                accp[mt][0] = __builtin_amdgcn_mfma_f32_16x16x32_f16(af, bf[0], accp[mt][0], 0, 0, 0);
                accp[mt][1] = __builtin_amdgcn_mfma_f32_16x16x32_f16(af, bf[1], accp[mt][1], 0, 0, 0);
            }
        }
        __syncthreads();
    }

    float (*T)[132] = (float (*)[132])&A_sh[0][0];
    #pragma unroll
    for (int nt = 0; nt < 2; ++nt) {
        const int ch = nt*16 + l15;
        if (ch < 27) {
            #pragma unroll
            for (int mt = 0; mt < 2; ++mt)
                #pragma unroll
                for (int r = 0; r < 4; ++r)
                    T[ch][wv*32 + mt*16 + quad*4 + r] = accp[mt][nt][r];
        }
    }
    __syncthreads();

    float dyk[9], dxk[9], mkk[9];
    float* offp = offset_out + (size_t)b*18*HWSZ + pix0;
    #pragma unroll
    for (int k = 0; k < 9; ++k) {
        dyk[k] = T[2*k][p]   + p_b[2*k];
        dxk[k] = T[2*k+1][p] + p_b[2*k+1];
        mkk[k] = 1.f / (1.f + expf(-(T[18+k][p] + m_b[k])));
    }
    if (tid < 128) {
        #pragma unroll
        for (int k = 0; k < 9; ++k) {
            offp[(2*k  )*HWSZ + p] = dyk[k];
            offp[(2*k+1)*HWSZ + p] = dxk[k];
        }
    }
    __syncthreads();

    floatx4 acc[2][4];
    #pragma unroll
    for (int mt = 0; mt < 2; ++mt)
        #pragma unroll
        for (int nt = 0; nt < 4; ++nt) acc[mt][nt] = (floatx4)0.f;

    for (int k = 0; k < 9; ++k) {
        {
            const int o  = tid >> 2;
            const int c0 = (tid & 3) * 16;
            const _Float16* src = Wd + k*4096 + o*64 + c0;
            *(half8*)&Wd_sh[o][c0]     = *(const half8*)src;
            *(half8*)&Wd_sh[o][c0 + 8] = *(const half8*)(src + 8);
        }
        const float mk = mkk[k];
        const float py = (float)(h - 1 + k/3) + dyk[k];
        const float px = (float)(w - 1 + k%3) + dxk[k];
        const float y0f = floorf(py), x0f = floorf(px);
        const int   iy0 = (int)y0f,   ix0 = (int)x0f;
        const float wy1 = py - y0f,   wx1 = px - x0f;
        const float wy0 = 1.f - wy1,  wx0 = 1.f - wx1;
        const bool vy0 = (iy0   >= 0) & (iy0   < HH);
        const bool vy1 = (iy0+1 >= 0) & (iy0+1 < HH);
        const bool vx0 = (ix0   >= 0) & (ix0   < WW);
        const bool vx1 = (ix0+1 >= 0) & (ix0+1 < WW);
        const int cy0 = min(max(iy0,   0), HH-1), cy1 = min(max(iy0+1, 0), HH-1);
        const int cx0 = min(max(ix0,   0), WW-1), cx1 = min(max(ix0+1, 0), WW-1);
        const int i0 = cy0*WW+cx0; const float w0 = wy0*wx0*((vy0&vx0) ? mk : 0.f);
        const int i1 = cy0*WW+cx1; const float w1 = wy0*wx1*((vy0&vx1) ? mk : 0.f);
        const int i2 = cy1*WW+cx0; const float w2 = wy1*wx0*((vy1&vx0) ? mk : 0.f);
        const int i3 = cy1*WW+cx1; const float w3 = wy1*wx1*((vy1&vx1) ? mk : 0.f);
        #pragma unroll
        for (int cb = 0; cb < 4; ++cb) {
            union { half8 v; _Float16 e[8]; } u;
            #pragma unroll
            for (int j = 0; j < 8; ++j) {
                const float* xc = xb + (size_t)(chalf + cb*8 + j)*HWSZ;
                u.e[j] = (_Float16)(w0*xc[i0] + w1*xc[i1] + w2*xc[i2] + w3*xc[i3]);
            }
            *(half8*)&A_sh[p][chalf + cb*8] = u.v;
        }
        __syncthreads();
        #pragma unroll
        for (int ks = 0; ks < 2; ++ks) {
            half8 bf[4];
            #pragma unroll
            for (int nt = 0; nt < 4; ++nt)
                bf[nt] = *(const half8*)&Wd_sh[nt*16 + l15][ks*32 + quad*8];
            #pragma unroll
            for (int mt = 0; mt < 2; ++mt) {
                half8 af = *(const half8*)&A_sh[wv*32 + mt*16 + l15][ks*32 + quad*8];
                #pragma unroll
                for (int nt = 0; nt < 4; ++nt)
                    acc[mt][nt] = __builtin_amdgcn_mfma_f32_16x16x32_f16(af, bf[nt], acc[mt][nt], 0, 0, 0);
            }
        }
        __syncthreads();
    }

    float (*T2)[132] = (float (*)[132])&A_sh[0][0];
    #pragma unroll
    for (int oc = 0; oc < 4; ++oc) {
        #pragma unroll
        for (int mt = 0; mt < 2; ++mt)
            #pragma unroll
            for (int r = 0; r < 4; ++r)
                T2[l15][wv*32 + mt*16 + quad*4 + r] = acc[mt][oc][r];
        __syncthreads();
        #pragma unroll
        for (int j = 0; j < 8; ++j) {
            const int idx = tid + j*256;
            const int o16 = idx >> 7, p2 = idx & 127;
            out[((size_t)b*OO + oc*16 + o16)*HWSZ + pix0 + p2] = T2[o16][p2] + db[oc*16 + o16];
        }
        __syncthreads();
    }
}

extern "C" void kernel_launch(void* const* d_in, const int* in_sizes, int n_in,
                              void* d_out, int out_size, void* d_ws, size_t ws_size,
                              hipStream_t stream) {
    const float* x   = (const float*)d_in[0];
    const float* p_w = (const float*)d_in[1];
    const float* p_b = (const float*)d_in[2];
    const float* m_w = (const float*)d_in[3];
    const float* m_b = (const float*)d_in[4];
    const float* dw  = (const float*)d_in[5];
    const float* db  = (const float*)d_in[6];

    float* out        = (float*)d_out;             // (B,O,H,W)
    float* offset_out = out + (size_t)BB*OO*HWSZ;  // (B,18,H,W)

    _Float16* Wp  = (_Float16*)d_ws;
    _Float16* Wd  = Wp + WP_ELEMS;
    _Float16* x_h = Wd + WD_ELEMS;

    const int nrep = (WP_ELEMS + WD_ELEMS + 255) / 256;
    const size_t need = (size_t)(WP_ELEMS + WD_ELEMS + XH_ELEMS) * sizeof(_Float16);
    if (ws_size >= need) {
        prep<<<dim3(NCONV + nrep), 256, 0, stream>>>(x, p_w, m_w, dw, Wp, Wd, x_h);
        dcn_fused<<<dim3(128*BB), 256, 0, stream>>>(x_h, Wp, Wd, p_b, m_b, db, out, offset_out);
    } else {
        prep<<<dim3(nrep), 256, 0, stream>>>(x, p_w, m_w, dw, Wp, Wd, x_h);  // repack only won't run convert blocks
        dcn_fused_lds<<<dim3(128*BB), 256, 0, stream>>>(x, Wp, Wd, p_b, m_b, db, out, offset_out);
    }
}

// Round 7
// 186.024 us; speedup vs baseline: 1.3478x; 1.3478x over previous
//
#include <hip/hip_runtime.h>
#include <math.h>

#define KK 9
#define BB 8
#define CC 64
#define OO 64
#define HH 128
#define WW 128
#define HWSZ (HH*WW)

typedef _Float16 half8 __attribute__((ext_vector_type(8)));
typedef float    floatx4 __attribute__((ext_vector_type(4)));

// ws layout (f16): Wp[32][576] | Wd[9][64][64] | x_h[B][HW][64]
#define WP_ELEMS (32*576)
#define WD_ELEMS (9*64*64)
#define XH_ELEMS ((size_t)BB*HWSZ*64)
#define NCONV 2048

// ---------------- prep: x -> channel-last f16 (+ weight repack) ----------------
__global__ __launch_bounds__(256) void prep(
    const float* __restrict__ x,
    const float* __restrict__ p_w, const float* __restrict__ m_w,
    const float* __restrict__ d_w,
    _Float16* __restrict__ Wp, _Float16* __restrict__ Wd, _Float16* __restrict__ x_h,
    int conv_blocks)
{
    const int blk = blockIdx.x;
    const int tid = threadIdx.x;
    if (blk < conv_blocks) {
        __shared__ _Float16 sh[64][72];
        const int b    = blk >> 8;
        const int pix0 = (blk & 255) * 64;
        const float* xb = x + (size_t)b*CC*HWSZ + pix0;
        {
            const int p     = tid & 63;
            const int cbase = tid >> 6;
            #pragma unroll
            for (int j = 0; j < 16; ++j) {
                const int c = j*4 + cbase;
                sh[p][c] = (_Float16)xb[(size_t)c*HWSZ + p];
            }
        }
        __syncthreads();
        {
            const int p  = tid >> 2;
            const int c0 = (tid & 3) * 16;
            _Float16* dst = x_h + ((size_t)b*HWSZ + pix0 + p)*64 + c0;
            *(half8*)dst       = *(const half8*)&sh[p][c0];
            *(half8*)(dst + 8) = *(const half8*)&sh[p][c0 + 8];
        }
    } else {
        const int i = (blk - conv_blocks)*256 + tid;
        if (i < WP_ELEMS) {
            int n = i / 576, r = i % 576;
            int k = r >> 6, c = r & 63;
            float v = 0.f;
            if (n < 18)      v = p_w[(n*CC + c)*KK + k];
            else if (n < 27) v = m_w[((n-18)*CC + c)*KK + k];
            Wp[i] = (_Float16)v;
        } else if (i < WP_ELEMS + WD_ELEMS) {
            int j = i - WP_ELEMS;
            int k = j / 4096, r = j % 4096, o = r >> 6, c = r & 63;  // Wd[k][o][c]
            Wd[j] = (_Float16)d_w[(o*CC + c)*KK + k];
        }
    }
}

// ---------------- fused DCNv2, LDS-staged MFMA with cross-tap prefetch ----------------
// grid 1024 (b = blk&7 XCD swizzle, row = blk>>3); block 512 = 8 waves.
// Staging: 4 threads/pixel (16 ch each). MFMA: wave wv owns pixels wv*16..wv*16+15.
__global__ __launch_bounds__(512, 4) void dcn_fused(
    const _Float16* __restrict__ x_h,
    const _Float16* __restrict__ Wp, const _Float16* __restrict__ Wd,
    const float* __restrict__ p_b, const float* __restrict__ m_b,
    const float* __restrict__ db,
    float* __restrict__ out, float* __restrict__ offset_out)
{
    __shared__ alignas(16) char smem[128*72*2 + 64*72*2];   // A region 18432B | W region 9216B
    _Float16* AS = (_Float16*)smem;                 // [128][72]
    _Float16* WS = (_Float16*)(smem + 128*72*2);    // [64][72] (phase1 uses rows 0..31)

    const int tid  = threadIdx.x;
    const int wv   = tid >> 6;
    const int lane = tid & 63;
    const int quad = lane >> 4;
    const int l15  = lane & 15;
    const int p    = tid & 127;        // pixel in row (w coord)
    const int cq   = tid >> 7;         // channel quarter 0..3 (16 ch)
    const int b    = blockIdx.x & 7;
    const int row  = blockIdx.x >> 3;
    const int pix0 = row * WW;
    const _Float16* xbh = x_h + (size_t)b*HWSZ*64;

    // =============== phase 1: offset(18)+mask(9) conv, pipelined ===============
    half8 q0, q1, pw1;
    bool vldc = false;
    auto issue1 = [&](int k) {
        const int hy = row + k/3 - 1;
        const int wx = p   + k%3 - 1;
        vldc = (hy >= 0) & (hy < HH) & (wx >= 0) & (wx < WW);
        const _Float16* ap = xbh + (size_t)(vldc ? hy*WW + wx : 0)*64 + cq*16;
        q0 = *(const half8*)ap;
        q1 = *(const half8*)(ap + 8);
        if (tid < 256)
            pw1 = *(const half8*)(Wp + (tid>>3)*576 + k*64 + (tid&7)*8);
    };

    floatx4 accp[2];
    accp[0] = (floatx4)0.f; accp[1] = (floatx4)0.f;

    issue1(0);
    #pragma unroll
    for (int k = 0; k < 9; ++k) {
        if (tid < 256)
            *(half8*)&WS[(tid>>3)*72 + (tid&7)*8] = pw1;
        const half8 z = (half8)(_Float16)0.f;
        *(half8*)&AS[p*72 + cq*16]     = vldc ? q0 : z;
        *(half8*)&AS[p*72 + cq*16 + 8] = vldc ? q1 : z;
        __syncthreads();
        if (k < 8) issue1(k+1);
        #pragma unroll
        for (int ks = 0; ks < 2; ++ks) {
            half8 bf0 = *(const half8*)&WS[(l15     )*72 + ks*32 + quad*8];
            half8 bf1 = *(const half8*)&WS[(16 + l15)*72 + ks*32 + quad*8];
            half8 af  = *(const half8*)&AS[(wv*16 + l15)*72 + ks*32 + quad*8];
            accp[0] = __builtin_amdgcn_mfma_f32_16x16x32_f16(af, bf0, accp[0], 0, 0, 0);
            accp[1] = __builtin_amdgcn_mfma_f32_16x16x32_f16(af, bf1, accp[1], 0, 0, 0);
        }
        __syncthreads();
    }

    // epilogue 1: D-frags -> T (fp32, aliases AS), offsets -> regs + global, mask -> regs
    float* T = (float*)AS;   // [27][132]
    #pragma unroll
    for (int nt = 0; nt < 2; ++nt) {
        const int ch = nt*16 + l15;
        if (ch < 27) {
            #pragma unroll
            for (int r = 0; r < 4; ++r)
                T[ch*132 + wv*16 + quad*4 + r] = accp[nt][r];
        }
    }
    __syncthreads();

    float dyk[9], dxk[9], mkk[9];
    #pragma unroll
    for (int k = 0; k < 9; ++k) {
        dyk[k] = T[(2*k  )*132 + p] + p_b[2*k];
        dxk[k] = T[(2*k+1)*132 + p] + p_b[2*k+1];
        mkk[k] = 1.f / (1.f + expf(-(T[(18+k)*132 + p] + m_b[k])));
    }
    {
        float* offp = offset_out + (size_t)b*18*HWSZ + pix0;
        #pragma unroll
        for (int j = 0; j < 5; ++j) {
            const int idx = j*512 + tid;
            if (idx < 2304) {
                const int ch = idx >> 7, px = idx & 127;
                offp[ch*HWSZ + px] = T[ch*132 + px] + p_b[ch];
            }
        }
    }
    __syncthreads();

    // =============== phase 2: modulated deformable conv, pipelined ===============
    half8 pa[8], pwv;
    float phw[4];
    auto issue2 = [&](int k) {
        const float py = (float)(row - 1 + k/3) + dyk[k];
        const float px = (float)(p   - 1 + k%3) + dxk[k];
        const float mk = mkk[k];
        const float y0f = floorf(py), x0f = floorf(px);
        const int   iy0 = (int)y0f,   ix0 = (int)x0f;
        const float wy1 = py - y0f,   wx1 = px - x0f;
        const float wy0 = 1.f - wy1,  wx0 = 1.f - wx1;
        const bool vy0 = (iy0   >= 0) & (iy0   < HH);
        const bool vy1 = (iy0+1 >= 0) & (iy0+1 < HH);
        const bool vx0 = (ix0   >= 0) & (ix0   < WW);
        const bool vx1 = (ix0+1 >= 0) & (ix0+1 < WW);
        const int cy0 = min(max(iy0,   0), HH-1), cy1 = min(max(iy0+1, 0), HH-1);
        const int cx0 = min(max(ix0,   0), WW-1), cx1 = min(max(ix0+1, 0), WW-1);
        const int i0 = cy0*WW+cx0, i1 = cy0*WW+cx1, i2 = cy1*WW+cx0, i3 = cy1*WW+cx1;
        phw[0] = wy0*wx0*((vy0&vx0) ? mk : 0.f);
        phw[1] = wy0*wx1*((vy0&vx1) ? mk : 0.f);
        phw[2] = wy1*wx0*((vy1&vx0) ? mk : 0.f);
        phw[3] = wy1*wx1*((vy1&vx1) ? mk : 0.f);
        const _Float16* c0p = xbh + (size_t)i0*64 + cq*16;
        const _Float16* c1p = xbh + (size_t)i1*64 + cq*16;
        const _Float16* c2p = xbh + (size_t)i2*64 + cq*16;
        const _Float16* c3p = xbh + (size_t)i3*64 + cq*16;
        pa[0] = *(const half8*)c0p;  pa[1] = *(const half8*)(c0p + 8);
        pa[2] = *(const half8*)c1p;  pa[3] = *(const half8*)(c1p + 8);
        pa[4] = *(const half8*)c2p;  pa[5] = *(const half8*)(c2p + 8);
        pa[6] = *(const half8*)c3p;  pa[7] = *(const half8*)(c3p + 8);
        pwv = *(const half8*)(Wd + k*4096 + tid*8);
    };

    floatx4 acc[4];
    #pragma unroll
    for (int nt = 0; nt < 4; ++nt) acc[nt] = (floatx4)0.f;

    issue2(0);
    #pragma unroll
    for (int k = 0; k < 9; ++k) {
        *(half8*)&WS[(tid>>3)*72 + (tid&7)*8] = pwv;
        const _Float16 g0 = (_Float16)phw[0], g1 = (_Float16)phw[1],
                       g2 = (_Float16)phw[2], g3 = (_Float16)phw[3];
        half8 lo = pa[0]*g0 + pa[2]*g1 + pa[4]*g2 + pa[6]*g3;
        half8 hi = pa[1]*g0 + pa[3]*g1 + pa[5]*g2 + pa[7]*g3;
        *(half8*)&AS[p*72 + cq*16]     = lo;
        *(half8*)&AS[p*72 + cq*16 + 8] = hi;
        __syncthreads();
        if (k < 8) issue2(k+1);
        #pragma unroll
        for (int ks = 0; ks < 2; ++ks) {
            half8 af = *(const half8*)&AS[(wv*16 + l15)*72 + ks*32 + quad*8];
            #pragma unroll
            for (int nt = 0; nt < 4; ++nt) {
                half8 bf = *(const half8*)&WS[(nt*16 + l15)*72 + ks*32 + quad*8];
                acc[nt] = __builtin_amdgcn_mfma_f32_16x16x32_f16(af, bf, acc[nt], 0, 0, 0);
            }
        }
        __syncthreads();
    }

    // epilogue 2: 4 chunks of 16 output channels via LDS transpose
    float* T2 = (float*)AS;   // [16][132]
    #pragma unroll
    for (int oc = 0; oc < 4; ++oc) {
        #pragma unroll
        for (int r = 0; r < 4; ++r)
            T2[l15*132 + wv*16 + quad*4 + r] = acc[oc][r];
        __syncthreads();
        #pragma unroll
        for (int j = 0; j < 4; ++j) {
            const int idx = j*512 + tid;
            const int o16 = idx >> 7, p2 = idx & 127;
            out[((size_t)b*OO + oc*16 + o16)*HWSZ + pix0 + p2] = T2[o16*132 + p2] + db[oc*16 + o16];
        }
        __syncthreads();
    }
}

// ---------------- fallback (ws too small): R5-style LDS kernel, fp32 gather ----------------
__global__ __launch_bounds__(256, 4) void dcn_fused_lds(
    const float* __restrict__ x,
    const _Float16* __restrict__ Wp, const _Float16* __restrict__ Wd,
    const float* __restrict__ p_b, const float* __restrict__ m_b,
    const float* __restrict__ db,
    float* __restrict__ out, float* __restrict__ offset_out)
{
    __shared__ alignas(16) _Float16 A_sh[128][72];
    __shared__ alignas(16) _Float16 WM_sh[32*72];
    __shared__ alignas(16) _Float16 Wd_sh[64][72];

    const int tid   = threadIdx.x;
    const int wv    = tid >> 6;
    const int lane  = tid & 63;
    const int quad  = lane >> 4;
    const int l15   = lane & 15;
    const int b     = blockIdx.x & 7;
    const int row   = blockIdx.x >> 3;
    const int pix0  = row * WW;
    const int p     = tid & 127;
    const int chalf = (tid >> 7) * 32;
    const int h = row, w = p;
    const float* xb = x + (size_t)b*CC*HWSZ;
    _Float16 (*W_sh)[72] = (_Float16 (*)[72])WM_sh;

    floatx4 accp[2][2];
    #pragma unroll
    for (int mt = 0; mt < 2; ++mt)
        #pragma unroll
        for (int nt = 0; nt < 2; ++nt) accp[mt][nt] = (floatx4)0.f;

    for (int k = 0; k < 9; ++k) {
        {
            const int n  = tid >> 3;
            const int c0 = (tid & 7) * 8;
            *(half8*)&W_sh[n][c0] = *(const half8*)(Wp + n*576 + k*64 + c0);
        }
        const int hy = h + (k/3) - 1;
        const int wx = w + (k%3) - 1;
        const bool vld = (hy >= 0) & (hy < HH) & (wx >= 0) & (wx < WW);
        const float* xs = xb + hy*WW + wx;
        #pragma unroll
        for (int cb = 0; cb < 4; ++cb) {
            union { half8 v; _Float16 e[8]; } u;
            #pragma unroll
            for (int j = 0; j < 8; ++j)
                u.e[j] = (_Float16)(vld ? xs[(size_t)(chalf + cb*8 + j)*HWSZ] : 0.f);
            *(half8*)&A_sh[p][chalf + cb*8] = u.v;
        }
        __syncthreads();
        #pragma unroll
        for (int ks = 0; ks < 2; ++ks) {
            half8 bf[2];
            #pragma unroll
            for (int nt = 0; nt < 2; ++nt)
                bf[nt] = *(const half8*)&W_sh[nt*16 + l15][ks*32 + quad*8];
            #pragma unroll
            for (int mt = 0; mt < 2; ++mt) {
                half8 af = *(const half8*)&A_sh[wv*32 + mt*16 + l15][ks*32 + quad*8];
                accp[mt][0] = __builtin_amdgcn_mfma_f32_16x16x32_f16(af, bf[0], accp[mt][0], 0, 0, 0);
                accp[mt][1] = __builtin_amdgcn_mfma_f32_16x16x32_f16(af, bf[1], accp[mt][1], 0, 0, 0);
            }
        }
        __syncthreads();
    }

    float (*T)[132] = (float (*)[132])&A_sh[0][0];
    #pragma unroll
    for (int nt = 0; nt < 2; ++nt) {
        const int ch = nt*16 + l15;
        if (ch < 27) {
            #pragma unroll
            for (int mt = 0; mt < 2; ++mt)
                #pragma unroll
                for (int r = 0; r < 4; ++r)
                    T[ch][wv*32 + mt*16 + quad*4 + r] = accp[mt][nt][r];
        }
    }
    __syncthreads();

    float dyk[9], dxk[9], mkk[9];
    float* offp = offset_out + (size_t)b*18*HWSZ + pix0;
    #pragma unroll
    for (int k = 0; k < 9; ++k) {
        dyk[k] = T[2*k][p]   + p_b[2*k];
        dxk[k] = T[2*k+1][p] + p_b[2*k+1];
        mkk[k] = 1.f / (1.f + expf(-(T[18+k][p] + m_b[k])));
    }
    if (tid < 128) {
        #pragma unroll
        for (int k = 0; k < 9; ++k) {
            offp[(2*k  )*HWSZ + p] = dyk[k];
            offp[(2*k+1)*HWSZ + p] = dxk[k];
        }
    }
    __syncthreads();

    floatx4 acc[2][4];
    #pragma unroll
    for (int mt = 0; mt < 2; ++mt)
        #pragma unroll
        for (int nt = 0; nt < 4; ++nt) acc[mt][nt] = (floatx4)0.f;

    for (int k = 0; k < 9; ++k) {
        {
            const int o  = tid >> 2;
            const int c0 = (tid & 3) * 16;
            const _Float16* src = Wd + k*4096 + o*64 + c0;
            *(half8*)&Wd_sh[o][c0]     = *(const half8*)src;
            *(half8*)&Wd_sh[o][c0 + 8] = *(const half8*)(src + 8);
        }
        const float mk = mkk[k];
        const float py = (float)(h - 1 + k/3) + dyk[k];
        const float px = (float)(w - 1 + k%3) + dxk[k];
        const float y0f = floorf(py), x0f = floorf(px);
        const int   iy0 = (int)y0f,   ix0 = (int)x0f;
        const float wy1 = py - y0f,   wx1 = px - x0f;
        const float wy0 = 1.f - wy1,  wx0 = 1.f - wx1;
        const bool vy0 = (iy0   >= 0) & (iy0   < HH);
        const bool vy1 = (iy0+1 >= 0) & (iy0+1 < HH);
        const bool vx0 = (ix0   >= 0) & (ix0   < WW);
        const bool vx1 = (ix0+1 >= 0) & (ix0+1 < WW);
        const int cy0 = min(max(iy0,   0), HH-1), cy1 = min(max(iy0+1, 0), HH-1);
        const int cx0 = min(max(ix0,   0), WW-1), cx1 = min(max(ix0+1, 0), WW-1);
        const int i0 = cy0*WW+cx0; const float w0 = wy0*wx0*((vy0&vx0) ? mk : 0.f);
        const int i1 = cy0*WW+cx1; const float w1 = wy0*wx1*((vy0&vx1) ? mk : 0.f);
        const int i2 = cy1*WW+cx0; const float w2 = wy1*wx0*((vy1&vx0) ? mk : 0.f);
        const int i3 = cy1*WW+cx1; const float w3 = wy1*wx1*((vy1&vx1) ? mk : 0.f);
        #pragma unroll
        for (int cb = 0; cb < 4; ++cb) {
            union { half8 v; _Float16 e[8]; } u;
            #pragma unroll
            for (int j = 0; j < 8; ++j) {
                const float* xc = xb + (size_t)(chalf + cb*8 + j)*HWSZ;
                u.e[j] = (_Float16)(w0*xc[i0] + w1*xc[i1] + w2*xc[i2] + w3*xc[i3]);
            }
            *(half8*)&A_sh[p][chalf + cb*8] = u.v;
        }
        __syncthreads();
        #pragma unroll
        for (int ks = 0; ks < 2; ++ks) {
            half8 bf[4];
            #pragma unroll
            for (int nt = 0; nt < 4; ++nt)
                bf[nt] = *(const half8*)&Wd_sh[nt*16 + l15][ks*32 + quad*8];
            #pragma unroll
            for (int mt = 0; mt < 2; ++mt) {
                half8 af = *(const half8*)&A_sh[wv*32 + mt*16 + l15][ks*32 + quad*8];
                #pragma unroll
                for (int nt = 0; nt < 4; ++nt)
                    acc[mt][nt] = __builtin_amdgcn_mfma_f32_16x16x32_f16(af, bf[nt], acc[mt][nt], 0, 0, 0);
            }
        }
        __syncthreads();
    }

    float (*T2)[132] = (float (*)[132])&A_sh[0][0];
    #pragma unroll
    for (int oc = 0; oc < 4; ++oc) {
        #pragma unroll
        for (int mt = 0; mt < 2; ++mt)
            #pragma unroll
            for (int r = 0; r < 4; ++r)
                T2[l15][wv*32 + mt*16 + quad*4 + r] = acc[mt][oc][r];
        __syncthreads();
        #pragma unroll
        for (int j = 0; j < 8; ++j) {
            const int idx = tid + j*256;
            const int o16 = idx >> 7, p2 = idx & 127;
            out[((size_t)b*OO + oc*16 + o16)*HWSZ + pix0 + p2] = T2[o16][p2] + db[oc*16 + o16];
        }
        __syncthreads();
    }
}

extern "C" void kernel_launch(void* const* d_in, const int* in_sizes, int n_in,
                              void* d_out, int out_size, void* d_ws, size_t ws_size,
                              hipStream_t stream) {
    const float* x   = (const float*)d_in[0];
    const float* p_w = (const float*)d_in[1];
    const float* p_b = (const float*)d_in[2];
    const float* m_w = (const float*)d_in[3];
    const float* m_b = (const float*)d_in[4];
    const float* dw  = (const float*)d_in[5];
    const float* db  = (const float*)d_in[6];

    float* out        = (float*)d_out;             // (B,O,H,W)
    float* offset_out = out + (size_t)BB*OO*HWSZ;  // (B,18,H,W)

    _Float16* Wp  = (_Float16*)d_ws;
    _Float16* Wd  = Wp + WP_ELEMS;
    _Float16* x_h = Wd + WD_ELEMS;

    const int nrep = (WP_ELEMS + WD_ELEMS + 255) / 256;
    const size_t need = (size_t)(WP_ELEMS + WD_ELEMS + XH_ELEMS) * sizeof(_Float16);
    if (ws_size >= need) {
        prep<<<dim3(NCONV + nrep), 256, 0, stream>>>(x, p_w, m_w, dw, Wp, Wd, x_h, NCONV);
        dcn_fused<<<dim3(128*BB), 512, 0, stream>>>(x_h, Wp, Wd, p_b, m_b, db, out, offset_out);
    } else {
        prep<<<dim3(nrep), 256, 0, stream>>>(x, p_w, m_w, dw, Wp, Wd, x_h, 0);
        dcn_fused_lds<<<dim3(128*BB), 256, 0, stream>>>(x, Wp, Wd, p_b, m_b, db, out, offset_out);
    }
}